// Round 10
// baseline (164.543 us; speedup 1.0000x reference)
//
#include <hip/hip_runtime.h>
#include <cstdint>
#include <cstddef>

typedef __attribute__((ext_vector_type(4))) float f32x4;
typedef __attribute__((ext_vector_type(8))) short bf16x8;
typedef __attribute__((ext_vector_type(4))) unsigned int u32x4;

#define QSCALE 0.18033688011112042f   // 0.125 * log2(e) folded into Q projection
#define NSHIFT 17.3123404906676f      // 12 * log2(e): fixed softmax shift (scores ~ N(0,1))

static __device__ __forceinline__ unsigned short f2bf(float f) {
    return (unsigned short)((__builtin_bit_cast(unsigned int, f) + 0x8000u) >> 16);
}
static __device__ __forceinline__ unsigned int pk2(float a, float b) {
    unsigned int ua = __builtin_bit_cast(unsigned int, a) + 0x8000u;
    unsigned int ub = __builtin_bit_cast(unsigned int, b) + 0x8000u;
    return (ua >> 16) | (ub & 0xffff0000u);
}
static __device__ __forceinline__ unsigned int pack2h(float a, float b) {
    unsigned int ua = __builtin_bit_cast(unsigned int, a) + 0x8000u;
    unsigned int ub = __builtin_bit_cast(unsigned int, b) + 0x8000u;
    return __builtin_amdgcn_perm(ub, ua, 0x07060302);   // {ub.hi16, ua.hi16}
}
#if __has_builtin(__builtin_amdgcn_exp2f)
static __device__ __forceinline__ float fexp2(float x) { return __builtin_amdgcn_exp2f(x); }
#else
static __device__ __forceinline__ float fexp2(float x) { return exp2f(x); }
#endif
static __device__ __forceinline__ void glds16(const unsigned short* g, unsigned short* l) {
    __builtin_amdgcn_global_load_lds((const __attribute__((address_space(1))) void*)g,
                                     (__attribute__((address_space(3))) void*)l, 16, 0, 0);
}

// ---------------------------------------------------------------------------
// prep: (a) bx<1024: transpose+cast W[k][n]->Wt[n][k] bf16
//       (b) bx>=1024: cast X f32->bf16 row-major.  grid (3072, 3), block 256.
// ---------------------------------------------------------------------------
__global__ __launch_bounds__(256) void prep(
    const float* __restrict__ Wq, const float* __restrict__ Wk, const float* __restrict__ Wv,
    const float* __restrict__ Xq, const float* __restrict__ Xk, const float* __restrict__ Xv,
    unsigned short* __restrict__ Wt, unsigned short* __restrict__ Xb)
{
    const int z = blockIdx.y;
    if (blockIdx.x < 1024) {
        __shared__ float tile[32][33];
        const float* W = (z == 0) ? Wq : (z == 1) ? Wk : Wv;
        unsigned short* dst = Wt + (size_t)z * 1048576;
        int n0 = (blockIdx.x & 31) * 32, k0 = (blockIdx.x >> 5) * 32;
        int tx = threadIdx.x & 31, ty = threadIdx.x >> 5;
#pragma unroll
        for (int i = 0; i < 32; i += 8)
            tile[ty + i][tx] = W[(size_t)(k0 + ty + i) * 1024 + n0 + tx];
        __syncthreads();
#pragma unroll
        for (int i = 0; i < 32; i += 8)
            dst[(size_t)(n0 + ty + i) * 1024 + k0 + tx] = f2bf(tile[tx][ty + i]);
    } else {
        const float* X = (z == 0) ? Xq : (z == 1) ? Xk : Xv;
        unsigned short* dst = Xb + (size_t)z * 4194304;
        size_t base = (size_t)(blockIdx.x - 1024) * 2048 + threadIdx.x * 8;
        float4 a = *(const float4*)&X[base];
        float4 c = *(const float4*)&X[base + 4];
        *(int4*)&dst[base] = make_int4(pk2(a.x, a.y), pk2(a.z, a.w),
                                       pk2(c.x, c.y), pk2(c.z, c.w));
    }
}

// ---------------------------------------------------------------------------
// proj_g: m97-structure GEMM — both operands via global_load_lds(16B),
// pre-swizzled source, single-buffered LDS. 128x128, BK=64. grid (32, 8, 3).
// ---------------------------------------------------------------------------
__global__ __launch_bounds__(256, 3) void proj_g(
    const unsigned short* __restrict__ Xb, const unsigned short* __restrict__ Wt,
    const float* __restrict__ bq, const float* __restrict__ bk, const float* __restrict__ bv,
    const int* __restrict__ km, unsigned short* __restrict__ packs)
{
    const int mode = blockIdx.z;
    const unsigned short* X = Xb + (size_t)mode * 4194304;
    const unsigned short* W = Wt + (size_t)mode * 1048576;
    const float* bias = (mode == 0) ? bq : (mode == 1) ? bk : bv;
    unsigned short* outp = packs + (size_t)mode * 4194304;

    __shared__ alignas(16) unsigned short As[128 * 64];
    __shared__ alignas(16) unsigned short Bs[128 * 64];

    const int tid = threadIdx.x, wid = tid >> 6, lane = tid & 63;
    const int lrow = lane & 15, g = lane >> 4;
    const int m0 = blockIdx.x * 128, n0 = blockIdx.y * 128;
    const int wr = (wid >> 1) * 64, wc = (wid & 1) * 64;
    const int srow = tid >> 3;
    const int scol = ((tid & 7) ^ (srow & 7)) * 8;
    const int sdst = srow * 64 + (tid & 7) * 8;

    f32x4 acc[4][4] = {};

    for (int k0 = 0; k0 < 1024; k0 += 64) {
        __syncthreads();
#pragma unroll
        for (int p = 0; p < 4; ++p)
            glds16(&X[(size_t)(m0 + p * 32 + srow) * 1024 + k0 + scol], &As[p * 2048 + sdst]);
#pragma unroll
        for (int p = 0; p < 4; ++p)
            glds16(&W[(size_t)(n0 + p * 32 + srow) * 1024 + k0 + scol], &Bs[p * 2048 + sdst]);
        asm volatile("s_waitcnt vmcnt(0)" ::: "memory");
        __syncthreads();

#pragma unroll
        for (int kk = 0; kk < 2; ++kk) {
            bf16x8 af[4], bfr[4];
#pragma unroll
            for (int i = 0; i < 4; ++i)
                af[i] = *(const bf16x8*)&As[(wr + i * 16 + lrow) * 64 + (((kk * 4 + g) ^ (lrow & 7)) * 8)];
#pragma unroll
            for (int j = 0; j < 4; ++j)
                bfr[j] = *(const bf16x8*)&Bs[(wc + j * 16 + lrow) * 64 + (((kk * 4 + g) ^ (lrow & 7)) * 8)];
#pragma unroll
            for (int i = 0; i < 4; ++i)
#pragma unroll
                for (int j = 0; j < 4; ++j)
                    acc[i][j] = __builtin_amdgcn_mfma_f32_16x16x32_bf16(af[i], bfr[j], acc[i][j], 0, 0, 0);
        }
    }

#pragma unroll
    for (int j = 0; j < 4; ++j) {
        int n = n0 + wc + j * 16 + lrow;
        float bv_ = bias[n];
        int h = n >> 6, d = n & 63;
#pragma unroll
        for (int i = 0; i < 4; ++i) {
#pragma unroll
            for (int r = 0; r < 4; ++r) {
                int m = m0 + wr + i * 16 + g * 4 + r;
                float val = acc[i][j][r] + bv_;
                if (mode == 0) val *= QSCALE;
                int b = m >> 11, l = m & 2047;
                size_t idx;
                if (mode == 2) {
                    val *= (float)km[m];
                    idx = (((size_t)((b << 4) + h) << 6) + d) * 2048 + l;
                } else {
                    idx = (((size_t)((b << 4) + h) << 11) + l) * 64 + d;
                }
                outp[idx] = f2bf(val);
            }
        }
    }
}

// ---------------------------------------------------------------------------
// fallback path (if ws too small for Xb): transpose_w3 + proj_fb (R3-proven)
// ---------------------------------------------------------------------------
__global__ __launch_bounds__(256) void transpose_w3(
    const float* __restrict__ Wq, const float* __restrict__ Wk,
    const float* __restrict__ Wv, unsigned short* __restrict__ Wt)
{
    __shared__ float tile[32][33];
    const float* W = (blockIdx.z == 0) ? Wq : (blockIdx.z == 1) ? Wk : Wv;
    unsigned short* dst = Wt + (size_t)blockIdx.z * 1048576;
    int tx = threadIdx.x & 31, ty = threadIdx.x >> 5;
    int n0 = blockIdx.x * 32, k0 = blockIdx.y * 32;
#pragma unroll
    for (int i = 0; i < 32; i += 8)
        tile[ty + i][tx] = W[(size_t)(k0 + ty + i) * 1024 + n0 + tx];
    __syncthreads();
#pragma unroll
    for (int i = 0; i < 32; i += 8)
        dst[(size_t)(n0 + ty + i) * 1024 + k0 + tx] = f2bf(tile[tx][ty + i]);
}

__global__ __launch_bounds__(256, 3) void proj_fb(
    const float* __restrict__ Xq, const float* __restrict__ Xk, const float* __restrict__ Xv,
    const unsigned short* __restrict__ Wt,
    const float* __restrict__ bq, const float* __restrict__ bk, const float* __restrict__ bv,
    const int* __restrict__ km, unsigned short* __restrict__ packs)
{
    const int mode = blockIdx.z;
    const float* X = (mode == 0) ? Xq : (mode == 1) ? Xk : Xv;
    const unsigned short* W = Wt + (size_t)mode * 1048576;
    const float* bias = (mode == 0) ? bq : (mode == 1) ? bk : bv;
    unsigned short* outp = packs + (size_t)mode * 4194304;

    __shared__ alignas(16) unsigned short As[128 * 64];
    __shared__ alignas(16) unsigned short Bs[128 * 64];

    const int tid = threadIdx.x, wid = tid >> 6, lane = tid & 63;
    const int lrow = lane & 15, g = lane >> 4;
    const int m0 = blockIdx.x * 128, n0 = blockIdx.y * 128;
    const int wr = (wid >> 1) * 64, wc = (wid & 1) * 64;
    const int srow = tid >> 3;
    const int scol = ((tid & 7) ^ (srow & 7)) * 8;
    const int sdst = srow * 64 + (tid & 7) * 8;
    const int ar = tid >> 2;
    const int acb = (tid & 3) * 2;

    f32x4 acc[4][4] = {};

    for (int k0 = 0; k0 < 1024; k0 += 64) {
        __syncthreads();
#pragma unroll
        for (int p = 0; p < 4; ++p)
            glds16(&W[(size_t)(n0 + p * 32 + srow) * 1024 + k0 + scol], &Bs[p * 2048 + sdst]);
#pragma unroll
        for (int p = 0; p < 2; ++p) {
            int r = p * 64 + ar;
#pragma unroll
            for (int bl = 0; bl < 2; ++bl) {
                int cb = acb + bl;
                const float* src = &X[(size_t)(m0 + r) * 1024 + k0 + cb * 8];
                float4 v0 = *(const float4*)src;
                float4 v1 = *(const float4*)(src + 4);
                *(int4*)&As[r * 64 + ((cb ^ (r & 7)) * 8)] =
                    make_int4(pk2(v0.x, v0.y), pk2(v0.z, v0.w),
                              pk2(v1.x, v1.y), pk2(v1.z, v1.w));
            }
        }
        asm volatile("s_waitcnt vmcnt(0)" ::: "memory");
        __syncthreads();

#pragma unroll
        for (int kk = 0; kk < 2; ++kk) {
            bf16x8 af[4], bfr[4];
#pragma unroll
            for (int i = 0; i < 4; ++i)
                af[i] = *(const bf16x8*)&As[(wr + i * 16 + lrow) * 64 + (((kk * 4 + g) ^ (lrow & 7)) * 8)];
#pragma unroll
            for (int j = 0; j < 4; ++j)
                bfr[j] = *(const bf16x8*)&Bs[(wc + j * 16 + lrow) * 64 + (((kk * 4 + g) ^ (lrow & 7)) * 8)];
#pragma unroll
            for (int i = 0; i < 4; ++i)
#pragma unroll
                for (int j = 0; j < 4; ++j)
                    acc[i][j] = __builtin_amdgcn_mfma_f32_16x16x32_bf16(af[i], bfr[j], acc[i][j], 0, 0, 0);
        }
    }

#pragma unroll
    for (int j = 0; j < 4; ++j) {
        int n = n0 + wc + j * 16 + lrow;
        float bv_ = bias[n];
        int h = n >> 6, d = n & 63;
#pragma unroll
        for (int i = 0; i < 4; ++i) {
#pragma unroll
            for (int r = 0; r < 4; ++r) {
                int m = m0 + wr + i * 16 + g * 4 + r;
                float val = acc[i][j][r] + bv_;
                if (mode == 0) val *= QSCALE;
                int b = m >> 11, l = m & 2047;
                size_t idx;
                if (mode == 2) {
                    val *= (float)km[m];
                    idx = (((size_t)((b << 4) + h) << 6) + d) * 2048 + l;
                } else {
                    idx = (((size_t)((b << 4) + h) << 11) + l) * 64 + d;
                }
                outp[idx] = f2bf(val);
            }
        }
    }
}

// ---------------------------------------------------------------------------
// attn v4: grid (32, 32), 128 threads = 2 waves; each wave owns 32 q-rows.
// KV tile 64, pi-permuted key order (P stays in-register), fixed-shift
// softmax, lsum via mfma(P, mask), setprio on MFMA clusters.
// SINGLE-buffered Ks/Vs (m97 pattern): LDS 20.25 KB -> 7 blocks/CU
// (14 waves/CU) — occupancy replaces the explicit prefetch; 7 staggered
// block-streams per CU keep LDS/VALU/MFMA pipes overlapped (m114).
// ---------------------------------------------------------------------------
__global__ __launch_bounds__(128, 4) void attn(
    const unsigned short* __restrict__ Qp, const unsigned short* __restrict__ Kp,
    const unsigned short* __restrict__ Vtp, const int* __restrict__ km_g,
    float* __restrict__ out)
{
    __shared__ alignas(16) unsigned short Ks[64 * 64];   // [64 vrows][64 d]  8 KB
    __shared__ alignas(16) unsigned short Vs[64 * 64];   // [64 d][64 keys]   8 KB
    __shared__ alignas(16) unsigned short Ms[2048];      // mask bf16         4 KB

    const int tid = threadIdx.x, wid = tid >> 6, lane = tid & 63;
    const int lrow = lane & 15, g = lane >> 4;
    const int bh = blockIdx.y, b = bh >> 4, h = bh & 15;
    const int q0 = blockIdx.x * 64;
    const unsigned short* Q = Qp + (size_t)bh * 131072;
    const unsigned short* K = Kp + (size_t)bh * 131072;
    const unsigned short* V = Vtp + (size_t)bh * 131072;

    const int sr = lane >> 3;                       // 0..7
    const int b8 = lane & 7;
    const int sc = (b8 ^ sr) * 8;                   // pre-swizzled source col

    // key_mask -> bf16 LDS table (128 threads x 16 elems)
    {
        const int* km = km_g + b * 2048;
        unsigned int w[8];
#pragma unroll
        for (int p = 0; p < 4; ++p) {
            int4 a = *(const int4*)&km[tid * 16 + p * 4];
            w[p * 2]     = (a.x ? 0x3F80u : 0u) | ((a.y ? 0x3F80u : 0u) << 16);
            w[p * 2 + 1] = (a.z ? 0x3F80u : 0u) | ((a.w ? 0x3F80u : 0u) << 16);
        }
        *(int4*)&Ms[tid * 16]     = make_int4(w[0], w[1], w[2], w[3]);
        *(int4*)&Ms[tid * 16 + 8] = make_int4(w[4], w[5], w[6], w[7]);
    }

    // Q fragments for 2 q-subtiles (B-operand: col=q=lane&15, k=d)
    bf16x8 qf[2][2];
#pragma unroll
    for (int qs = 0; qs < 2; ++qs) {
        const unsigned short* qrow = Q + (size_t)(q0 + wid * 32 + qs * 16 + lrow) * 64;
        qf[qs][0] = *(const bf16x8*)(qrow + g * 8);
        qf[qs][1] = *(const bf16x8*)(qrow + 32 + g * 8);
    }

    auto STAGE = [&](int kt) {
        // K: pi-permuted key rows, 4 calls x 8 rows (each 1 KB linear)
#pragma unroll
        for (int i = 0; i < 4; ++i) {
            const int vr = wid * 32 + i * 8 + sr;
            const int pk = ((vr >> 4) & 1) * 32 + ((vr >> 2) & 3) * 8 + ((vr >> 5) & 1) * 4 + (vr & 3);
            glds16(&K[(size_t)(kt + pk) * 64 + sc], &Ks[vr * 64 + b8 * 8]);
        }
        // V: identity d-rows, 4 calls x 8 rows (source col pre-XOR'd by d&7=sr)
#pragma unroll
        for (int i = 0; i < 4; ++i) {
            const int d = wid * 32 + i * 8 + sr;
            glds16(&V[(size_t)d * 2048 + kt + sc], &Vs[d * 64 + b8 * 8]);
        }
    };

    f32x4 accO[2][4] = {};
    f32x4 accL[2] = {};
    const f32x4 sinit = {-NSHIFT, -NSHIFT, -NSHIFT, -NSHIFT};

    for (int t = 0; t < 32; ++t) {
        const int kt = t * 64;
        __syncthreads();                            // reads(t-1) done -> safe restage
        STAGE(kt);
        asm volatile("s_waitcnt vmcnt(0)" ::: "memory");
        __syncthreads();                            // writes(t) visible

        bf16x8 mf0 = *(const bf16x8*)&Ms[kt + g * 8];
        bf16x8 mf1 = *(const bf16x8*)&Ms[kt + 32 + g * 8];

        // S^T = K Q^T over permuted key rows; shift in acc init
        f32x4 accS[2][4];
        __builtin_amdgcn_s_setprio(1);
#pragma unroll
        for (int s = 0; s < 4; ++s) {
            const int krow = s * 16 + lrow;
            bf16x8 kf0 = *(const bf16x8*)&Ks[krow * 64 + ((g ^ (lrow & 7)) * 8)];
            bf16x8 kf1 = *(const bf16x8*)&Ks[krow * 64 + (((4 + g) ^ (lrow & 7)) * 8)];
#pragma unroll
            for (int qs = 0; qs < 2; ++qs) {
                accS[qs][s] = __builtin_amdgcn_mfma_f32_16x16x32_bf16(kf0, qf[qs][0], sinit, 0, 0, 0);
                accS[qs][s] = __builtin_amdgcn_mfma_f32_16x16x32_bf16(kf1, qf[qs][1], accS[qs][s], 0, 0, 0);
            }
        }
        __builtin_amdgcn_s_setprio(0);

        // P = exp2(S'); accS slots are PV A-fragment slots
        bf16x8 pf[2][2];
#pragma unroll
        for (int qs = 0; qs < 2; ++qs) {
            float e0[4], e1[4], e2[4], e3[4];
#pragma unroll
            for (int r = 0; r < 4; ++r) {
                e0[r] = fexp2(accS[qs][0][r]);
                e1[r] = fexp2(accS[qs][1][r]);
                e2[r] = fexp2(accS[qs][2][r]);
                e3[r] = fexp2(accS[qs][3][r]);
            }
            u32x4 t0 = {pack2h(e0[0], e0[1]), pack2h(e0[2], e0[3]),
                        pack2h(e2[0], e2[1]), pack2h(e2[2], e2[3])};
            u32x4 t1 = {pack2h(e1[0], e1[1]), pack2h(e1[2], e1[3]),
                        pack2h(e3[0], e3[1]), pack2h(e3[2], e3[3])};
            pf[qs][0] = __builtin_bit_cast(bf16x8, t0);
            pf[qs][1] = __builtin_bit_cast(bf16x8, t1);
        }

        // lsum + PV (vf shared across q-subtiles)
        __builtin_amdgcn_s_setprio(1);
#pragma unroll
        for (int qs = 0; qs < 2; ++qs) {
            accL[qs] = __builtin_amdgcn_mfma_f32_16x16x32_bf16(pf[qs][0], mf0, accL[qs], 0, 0, 0);
            accL[qs] = __builtin_amdgcn_mfma_f32_16x16x32_bf16(pf[qs][1], mf1, accL[qs], 0, 0, 0);
        }
#pragma unroll
        for (int j = 0; j < 4; ++j) {
            const int vrow = (j * 16 + lrow) * 64;
            bf16x8 vf0 = *(const bf16x8*)&Vs[vrow + ((g ^ (lrow & 7)) * 8)];
            bf16x8 vf1 = *(const bf16x8*)&Vs[vrow + (((4 + g) ^ (lrow & 7)) * 8)];
#pragma unroll
            for (int qs = 0; qs < 2; ++qs) {
                accO[qs][j] = __builtin_amdgcn_mfma_f32_16x16x32_bf16(pf[qs][0], vf0, accO[qs][j], 0, 0, 0);
                accO[qs][j] = __builtin_amdgcn_mfma_f32_16x16x32_bf16(pf[qs][1], vf1, accO[qs][j], 0, 0, 0);
            }
        }
        __builtin_amdgcn_s_setprio(0);
    }

    // out[b][q][h*64 + d]
#pragma unroll
    for (int qs = 0; qs < 2; ++qs)
#pragma unroll
        for (int j = 0; j < 4; ++j)
#pragma unroll
            for (int r = 0; r < 4; ++r) {
                int qq = q0 + wid * 32 + qs * 16 + g * 4 + r;
                out[((size_t)(b * 2048 + qq)) * 1024 + h * 64 + j * 16 + lrow] =
                    accO[qs][j][r] / accL[qs][r];
            }
}

// ---------------------------------------------------------------------------
extern "C" void kernel_launch(void* const* d_in, const int* in_sizes, int n_in,
                              void* d_out, int out_size, void* d_ws, size_t ws_size,
                              hipStream_t stream) {
    const float* query    = (const float*)d_in[0];
    const float* key      = (const float*)d_in[1];
    const float* value    = (const float*)d_in[2];
    const int*   key_mask = (const int*)d_in[3];
    const float* Wq = (const float*)d_in[4];
    const float* bq = (const float*)d_in[5];
    const float* Wk = (const float*)d_in[6];
    const float* bk = (const float*)d_in[7];
    const float* Wv = (const float*)d_in[8];
    const float* bv = (const float*)d_in[9];
    float* out = (float*)d_out;

    char* ws = (char*)d_ws;
    unsigned short* Wt = (unsigned short*)ws;                      //  6 MB
    unsigned short* Pk = (unsigned short*)(ws + 6291456);          // 24 MB
    unsigned short* Xb = (unsigned short*)(ws + 31457280);         // 24 MB (54 MB total)

    if (ws_size >= 56623104ull) {
        prep<<<dim3(3072, 3), 256, 0, stream>>>(Wq, Wk, Wv, query, key, value, Wt, Xb);
        proj_g<<<dim3(32, 8, 3), 256, 0, stream>>>(Xb, Wt, bq, bk, bv, key_mask, Pk);
    } else {
        transpose_w3<<<dim3(32, 32, 3), 256, 0, stream>>>(Wq, Wk, Wv, Wt);
        proj_fb<<<dim3(32, 8, 3), 256, 0, stream>>>(query, key, value, Wt, bq, bk, bv, key_mask, Pk);
    }
    attn<<<dim3(32, 32), 128, 0, stream>>>(Pk, Pk + 4194304, Pk + 8388608, key_mask, out);
}

// Round 11
// 107.587 us; speedup vs baseline: 1.5294x; 1.5294x over previous
//
#include <hip/hip_runtime.h>
#include <cstdint>
#include <cstddef>

typedef __attribute__((ext_vector_type(4))) float f32x4;
typedef __attribute__((ext_vector_type(8))) short bf16x8;
typedef __attribute__((ext_vector_type(4))) unsigned int u32x4;

#define QSCALE 0.18033688011112042f   // 0.125 * log2(e) folded into Q projection
#define NSHIFT 17.3123404906676f      // 12 * log2(e): fixed softmax shift (scores ~ N(0,1))

static __device__ __forceinline__ unsigned short f2bf(float f) {
    return (unsigned short)((__builtin_bit_cast(unsigned int, f) + 0x8000u) >> 16);
}
static __device__ __forceinline__ unsigned int pk2(float a, float b) {
    unsigned int ua = __builtin_bit_cast(unsigned int, a) + 0x8000u;
    unsigned int ub = __builtin_bit_cast(unsigned int, b) + 0x8000u;
    return (ua >> 16) | (ub & 0xffff0000u);
}
// packed bf16 convert: lo=cvt(a), hi=cvt(b). Inputs come from compiler-visible
// exp2f (TRANS) so hazard nops are compiler-inserted (T12 / m214v22 pattern).
static __device__ __forceinline__ unsigned int cvtpk(float a, float b) {
    unsigned int r;
    asm("v_cvt_pk_bf16_f32 %0, %1, %2" : "=v"(r) : "v"(a), "v"(b));
    return r;
}
#if __has_builtin(__builtin_amdgcn_exp2f)
static __device__ __forceinline__ float fexp2(float x) { return __builtin_amdgcn_exp2f(x); }
#else
static __device__ __forceinline__ float fexp2(float x) { return exp2f(x); }
#endif
static __device__ __forceinline__ void glds16(const unsigned short* g, unsigned short* l) {
    __builtin_amdgcn_global_load_lds((const __attribute__((address_space(1))) void*)g,
                                     (__attribute__((address_space(3))) void*)l, 16, 0, 0);
}

// ---------------------------------------------------------------------------
// prep: (a) bx<1024: transpose+cast W[k][n]->Wt[n][k] bf16
//       (b) bx>=1024: cast X f32->bf16 row-major.  grid (3072, 3), block 256.
// ---------------------------------------------------------------------------
__global__ __launch_bounds__(256) void prep(
    const float* __restrict__ Wq, const float* __restrict__ Wk, const float* __restrict__ Wv,
    const float* __restrict__ Xq, const float* __restrict__ Xk, const float* __restrict__ Xv,
    unsigned short* __restrict__ Wt, unsigned short* __restrict__ Xb)
{
    const int z = blockIdx.y;
    if (blockIdx.x < 1024) {
        __shared__ float tile[32][33];
        const float* W = (z == 0) ? Wq : (z == 1) ? Wk : Wv;
        unsigned short* dst = Wt + (size_t)z * 1048576;
        int n0 = (blockIdx.x & 31) * 32, k0 = (blockIdx.x >> 5) * 32;
        int tx = threadIdx.x & 31, ty = threadIdx.x >> 5;
#pragma unroll
        for (int i = 0; i < 32; i += 8)
            tile[ty + i][tx] = W[(size_t)(k0 + ty + i) * 1024 + n0 + tx];
        __syncthreads();
#pragma unroll
        for (int i = 0; i < 32; i += 8)
            dst[(size_t)(n0 + ty + i) * 1024 + k0 + tx] = f2bf(tile[tx][ty + i]);
    } else {
        const float* X = (z == 0) ? Xq : (z == 1) ? Xk : Xv;
        unsigned short* dst = Xb + (size_t)z * 4194304;
        size_t base = (size_t)(blockIdx.x - 1024) * 2048 + threadIdx.x * 8;
        float4 a = *(const float4*)&X[base];
        float4 c = *(const float4*)&X[base + 4];
        *(int4*)&dst[base] = make_int4(pk2(a.x, a.y), pk2(a.z, a.w),
                                       pk2(c.x, c.y), pk2(c.z, c.w));
    }
}

// ---------------------------------------------------------------------------
// proj_g: m97-structure GEMM — both operands via global_load_lds(16B),
// pre-swizzled source, single-buffered LDS. 128x128, BK=64. grid (32, 8, 3).
// ---------------------------------------------------------------------------
__global__ __launch_bounds__(256, 3) void proj_g(
    const unsigned short* __restrict__ Xb, const unsigned short* __restrict__ Wt,
    const float* __restrict__ bq, const float* __restrict__ bk, const float* __restrict__ bv,
    const int* __restrict__ km, unsigned short* __restrict__ packs)
{
    const int mode = blockIdx.z;
    const unsigned short* X = Xb + (size_t)mode * 4194304;
    const unsigned short* W = Wt + (size_t)mode * 1048576;
    const float* bias = (mode == 0) ? bq : (mode == 1) ? bk : bv;
    unsigned short* outp = packs + (size_t)mode * 4194304;

    __shared__ alignas(16) unsigned short As[128 * 64];
    __shared__ alignas(16) unsigned short Bs[128 * 64];

    const int tid = threadIdx.x, wid = tid >> 6, lane = tid & 63;
    const int lrow = lane & 15, g = lane >> 4;
    const int m0 = blockIdx.x * 128, n0 = blockIdx.y * 128;
    const int wr = (wid >> 1) * 64, wc = (wid & 1) * 64;
    const int srow = tid >> 3;
    const int scol = ((tid & 7) ^ (srow & 7)) * 8;
    const int sdst = srow * 64 + (tid & 7) * 8;

    f32x4 acc[4][4] = {};

    for (int k0 = 0; k0 < 1024; k0 += 64) {
        __syncthreads();
#pragma unroll
        for (int p = 0; p < 4; ++p)
            glds16(&X[(size_t)(m0 + p * 32 + srow) * 1024 + k0 + scol], &As[p * 2048 + sdst]);
#pragma unroll
        for (int p = 0; p < 4; ++p)
            glds16(&W[(size_t)(n0 + p * 32 + srow) * 1024 + k0 + scol], &Bs[p * 2048 + sdst]);
        asm volatile("s_waitcnt vmcnt(0)" ::: "memory");
        __syncthreads();

#pragma unroll
        for (int kk = 0; kk < 2; ++kk) {
            bf16x8 af[4], bfr[4];
#pragma unroll
            for (int i = 0; i < 4; ++i)
                af[i] = *(const bf16x8*)&As[(wr + i * 16 + lrow) * 64 + (((kk * 4 + g) ^ (lrow & 7)) * 8)];
#pragma unroll
            for (int j = 0; j < 4; ++j)
                bfr[j] = *(const bf16x8*)&Bs[(wc + j * 16 + lrow) * 64 + (((kk * 4 + g) ^ (lrow & 7)) * 8)];
#pragma unroll
            for (int i = 0; i < 4; ++i)
#pragma unroll
                for (int j = 0; j < 4; ++j)
                    acc[i][j] = __builtin_amdgcn_mfma_f32_16x16x32_bf16(af[i], bfr[j], acc[i][j], 0, 0, 0);
        }
    }

#pragma unroll
    for (int j = 0; j < 4; ++j) {
        int n = n0 + wc + j * 16 + lrow;
        float bv_ = bias[n];
        int h = n >> 6, d = n & 63;
#pragma unroll
        for (int i = 0; i < 4; ++i) {
#pragma unroll
            for (int r = 0; r < 4; ++r) {
                int m = m0 + wr + i * 16 + g * 4 + r;
                float val = acc[i][j][r] + bv_;
                if (mode == 0) val *= QSCALE;
                int b = m >> 11, l = m & 2047;
                size_t idx;
                if (mode == 2) {
                    val *= (float)km[m];
                    idx = (((size_t)((b << 4) + h) << 6) + d) * 2048 + l;
                } else {
                    idx = (((size_t)((b << 4) + h) << 11) + l) * 64 + d;
                }
                outp[idx] = f2bf(val);
            }
        }
    }
}

// ---------------------------------------------------------------------------
// fallback path (if ws too small for Xb): transpose_w3 + proj_fb (R3-proven)
// ---------------------------------------------------------------------------
__global__ __launch_bounds__(256) void transpose_w3(
    const float* __restrict__ Wq, const float* __restrict__ Wk,
    const float* __restrict__ Wv, unsigned short* __restrict__ Wt)
{
    __shared__ float tile[32][33];
    const float* W = (blockIdx.z == 0) ? Wq : (blockIdx.z == 1) ? Wk : Wv;
    unsigned short* dst = Wt + (size_t)blockIdx.z * 1048576;
    int tx = threadIdx.x & 31, ty = threadIdx.x >> 5;
    int n0 = blockIdx.x * 32, k0 = blockIdx.y * 32;
#pragma unroll
    for (int i = 0; i < 32; i += 8)
        tile[ty + i][tx] = W[(size_t)(k0 + ty + i) * 1024 + n0 + tx];
    __syncthreads();
#pragma unroll
    for (int i = 0; i < 32; i += 8)
        dst[(size_t)(n0 + ty + i) * 1024 + k0 + tx] = f2bf(tile[tx][ty + i]);
}

__global__ __launch_bounds__(256, 3) void proj_fb(
    const float* __restrict__ Xq, const float* __restrict__ Xk, const float* __restrict__ Xv,
    const unsigned short* __restrict__ Wt,
    const float* __restrict__ bq, const float* __restrict__ bk, const float* __restrict__ bv,
    const int* __restrict__ km, unsigned short* __restrict__ packs)
{
    const int mode = blockIdx.z;
    const float* X = (mode == 0) ? Xq : (mode == 1) ? Xk : Xv;
    const unsigned short* W = Wt + (size_t)mode * 1048576;
    const float* bias = (mode == 0) ? bq : (mode == 1) ? bk : bv;
    unsigned short* outp = packs + (size_t)mode * 4194304;

    __shared__ alignas(16) unsigned short As[128 * 64];
    __shared__ alignas(16) unsigned short Bs[128 * 64];

    const int tid = threadIdx.x, wid = tid >> 6, lane = tid & 63;
    const int lrow = lane & 15, g = lane >> 4;
    const int m0 = blockIdx.x * 128, n0 = blockIdx.y * 128;
    const int wr = (wid >> 1) * 64, wc = (wid & 1) * 64;
    const int srow = tid >> 3;
    const int scol = ((tid & 7) ^ (srow & 7)) * 8;
    const int sdst = srow * 64 + (tid & 7) * 8;
    const int ar = tid >> 2;
    const int acb = (tid & 3) * 2;

    f32x4 acc[4][4] = {};

    for (int k0 = 0; k0 < 1024; k0 += 64) {
        __syncthreads();
#pragma unroll
        for (int p = 0; p < 4; ++p)
            glds16(&W[(size_t)(n0 + p * 32 + srow) * 1024 + k0 + scol], &Bs[p * 2048 + sdst]);
#pragma unroll
        for (int p = 0; p < 2; ++p) {
            int r = p * 64 + ar;
#pragma unroll
            for (int bl = 0; bl < 2; ++bl) {
                int cb = acb + bl;
                const float* src = &X[(size_t)(m0 + r) * 1024 + k0 + cb * 8];
                float4 v0 = *(const float4*)src;
                float4 v1 = *(const float4*)(src + 4);
                *(int4*)&As[r * 64 + ((cb ^ (r & 7)) * 8)] =
                    make_int4(pk2(v0.x, v0.y), pk2(v0.z, v0.w),
                              pk2(v1.x, v1.y), pk2(v1.z, v1.w));
            }
        }
        asm volatile("s_waitcnt vmcnt(0)" ::: "memory");
        __syncthreads();

#pragma unroll
        for (int kk = 0; kk < 2; ++kk) {
            bf16x8 af[4], bfr[4];
#pragma unroll
            for (int i = 0; i < 4; ++i)
                af[i] = *(const bf16x8*)&As[(wr + i * 16 + lrow) * 64 + (((kk * 4 + g) ^ (lrow & 7)) * 8)];
#pragma unroll
            for (int j = 0; j < 4; ++j)
                bfr[j] = *(const bf16x8*)&Bs[(wc + j * 16 + lrow) * 64 + (((kk * 4 + g) ^ (lrow & 7)) * 8)];
#pragma unroll
            for (int i = 0; i < 4; ++i)
#pragma unroll
                for (int j = 0; j < 4; ++j)
                    acc[i][j] = __builtin_amdgcn_mfma_f32_16x16x32_bf16(af[i], bfr[j], acc[i][j], 0, 0, 0);
        }
    }

#pragma unroll
    for (int j = 0; j < 4; ++j) {
        int n = n0 + wc + j * 16 + lrow;
        float bv_ = bias[n];
        int h = n >> 6, d = n & 63;
#pragma unroll
        for (int i = 0; i < 4; ++i) {
#pragma unroll
            for (int r = 0; r < 4; ++r) {
                int m = m0 + wr + i * 16 + g * 4 + r;
                float val = acc[i][j][r] + bv_;
                if (mode == 0) val *= QSCALE;
                int b = m >> 11, l = m & 2047;
                size_t idx;
                if (mode == 2) {
                    val *= (float)km[m];
                    idx = (((size_t)((b << 4) + h) << 6) + d) * 2048 + l;
                } else {
                    idx = (((size_t)((b << 4) + h) << 11) + l) * 64 + d;
                }
                outp[idx] = f2bf(val);
            }
        }
    }
}

// ---------------------------------------------------------------------------
// attn v5 (= R9 structure + XCD swizzle + cvt_pk pack): grid (32, 32), 128
// threads = 2 waves; each wave owns 32 q-rows. KV tile 64, pi-permuted key
// order, DOUBLE-buffered glds16, fixed-shift softmax, lsum via mfma(P, mask),
// setprio on MFMA clusters. LDS 36.25 KB -> 4 blocks/CU.
// XCD-chunked bijective block swizzle: flat f=y*32+x, v=(f&7)*128+(f>>3)
// -> 4 consecutive heads' K/V (2 MB) live in one XCD's L2.
// ---------------------------------------------------------------------------
__global__ __launch_bounds__(128, 2) void attn(
    const unsigned short* __restrict__ Qp, const unsigned short* __restrict__ Kp,
    const unsigned short* __restrict__ Vtp, const int* __restrict__ km_g,
    float* __restrict__ out)
{
    __shared__ alignas(16) unsigned short Ks[2][64 * 64];   // [64 vrows][64 d]
    __shared__ alignas(16) unsigned short Vs[2][64 * 64];   // [64 d][64 keys]
    __shared__ alignas(16) unsigned short Ms[2048];         // mask bf16

    const int tid = threadIdx.x, wid = tid >> 6, lane = tid & 63;
    const int lrow = lane & 15, g = lane >> 4;
    // XCD-chunked bijective swizzle (1024 blocks, 8 XCDs, 128 per XCD)
    const int f = blockIdx.y * 32 + blockIdx.x;
    const int v = (f & 7) * 128 + (f >> 3);
    const int bh = v >> 5, b = bh >> 4, h = bh & 15;
    const int q0 = (v & 31) * 64;
    const unsigned short* Q = Qp + (size_t)bh * 131072;
    const unsigned short* K = Kp + (size_t)bh * 131072;
    const unsigned short* V = Vtp + (size_t)bh * 131072;

    const int sr = lane >> 3;                       // 0..7
    const int b8 = lane & 7;
    const int sc = (b8 ^ sr) * 8;                   // pre-swizzled source col

    // key_mask -> bf16 LDS table (128 threads x 16 elems)
    {
        const int* km = km_g + b * 2048;
        unsigned int w[8];
#pragma unroll
        for (int p = 0; p < 4; ++p) {
            int4 a = *(const int4*)&km[tid * 16 + p * 4];
            w[p * 2]     = (a.x ? 0x3F80u : 0u) | ((a.y ? 0x3F80u : 0u) << 16);
            w[p * 2 + 1] = (a.z ? 0x3F80u : 0u) | ((a.w ? 0x3F80u : 0u) << 16);
        }
        *(int4*)&Ms[tid * 16]     = make_int4(w[0], w[1], w[2], w[3]);
        *(int4*)&Ms[tid * 16 + 8] = make_int4(w[4], w[5], w[6], w[7]);
    }

    // Q fragments for 2 q-subtiles (B-operand: col=q=lane&15, k=d)
    bf16x8 qf[2][2];
#pragma unroll
    for (int qs = 0; qs < 2; ++qs) {
        const unsigned short* qrow = Q + (size_t)(q0 + wid * 32 + qs * 16 + lrow) * 64;
        qf[qs][0] = *(const bf16x8*)(qrow + g * 8);
        qf[qs][1] = *(const bf16x8*)(qrow + 32 + g * 8);
    }

    auto STAGE = [&](int buf, int kt) {
        // K: pi-permuted key rows, 4 calls x 8 rows (each 1 KB linear)
#pragma unroll
        for (int i = 0; i < 4; ++i) {
            const int vr = wid * 32 + i * 8 + sr;
            const int pk = ((vr >> 4) & 1) * 32 + ((vr >> 2) & 3) * 8 + ((vr >> 5) & 1) * 4 + (vr & 3);
            glds16(&K[(size_t)(kt + pk) * 64 + sc], &Ks[buf][vr * 64 + b8 * 8]);
        }
        // V: identity d-rows, 4 calls x 8 rows (source col pre-XOR'd by d&7=sr)
#pragma unroll
        for (int i = 0; i < 4; ++i) {
            const int d = wid * 32 + i * 8 + sr;
            glds16(&V[(size_t)d * 2048 + kt + sc], &Vs[buf][d * 64 + b8 * 8]);
        }
    };

    f32x4 accO[2][4] = {};
    f32x4 accL[2] = {};
    const f32x4 sinit = {-NSHIFT, -NSHIFT, -NSHIFT, -NSHIFT};

    STAGE(0, 0);
    for (int t = 0; t < 32; ++t) {
        const int cur = t & 1, kt = t * 64;
        asm volatile("s_waitcnt vmcnt(0)" ::: "memory");
        __syncthreads();
        if (t < 31) STAGE(cur ^ 1, kt + 64);

        bf16x8 mf0 = *(const bf16x8*)&Ms[kt + g * 8];
        bf16x8 mf1 = *(const bf16x8*)&Ms[kt + 32 + g * 8];

        // S^T = K Q^T over permuted key rows; shift in acc init
        f32x4 accS[2][4];
        __builtin_amdgcn_s_setprio(1);
#pragma unroll
        for (int s = 0; s < 4; ++s) {
            const int krow = s * 16 + lrow;
            bf16x8 kf0 = *(const bf16x8*)&Ks[cur][krow * 64 + ((g ^ (lrow & 7)) * 8)];
            bf16x8 kf1 = *(const bf16x8*)&Ks[cur][krow * 64 + (((4 + g) ^ (lrow & 7)) * 8)];
#pragma unroll
            for (int qs = 0; qs < 2; ++qs) {
                accS[qs][s] = __builtin_amdgcn_mfma_f32_16x16x32_bf16(kf0, qf[qs][0], sinit, 0, 0, 0);
                accS[qs][s] = __builtin_amdgcn_mfma_f32_16x16x32_bf16(kf1, qf[qs][1], accS[qs][s], 0, 0, 0);
            }
        }
        __builtin_amdgcn_s_setprio(0);

        // P = exp2(S'); accS slots are PV A-fragment slots; pack via cvt_pk
        bf16x8 pf[2][2];
#pragma unroll
        for (int qs = 0; qs < 2; ++qs) {
            float e0[4], e1[4], e2[4], e3[4];
#pragma unroll
            for (int r = 0; r < 4; ++r) {
                e0[r] = fexp2(accS[qs][0][r]);
                e1[r] = fexp2(accS[qs][1][r]);
                e2[r] = fexp2(accS[qs][2][r]);
                e3[r] = fexp2(accS[qs][3][r]);
            }
            u32x4 t0 = {cvtpk(e0[0], e0[1]), cvtpk(e0[2], e0[3]),
                        cvtpk(e2[0], e2[1]), cvtpk(e2[2], e2[3])};
            u32x4 t1 = {cvtpk(e1[0], e1[1]), cvtpk(e1[2], e1[3]),
                        cvtpk(e3[0], e3[1]), cvtpk(e3[2], e3[3])};
            pf[qs][0] = __builtin_bit_cast(bf16x8, t0);
            pf[qs][1] = __builtin_bit_cast(bf16x8, t1);
        }

        // lsum + PV (vf shared across q-subtiles)
        __builtin_amdgcn_s_setprio(1);
#pragma unroll
        for (int qs = 0; qs < 2; ++qs) {
            accL[qs] = __builtin_amdgcn_mfma_f32_16x16x32_bf16(pf[qs][0], mf0, accL[qs], 0, 0, 0);
            accL[qs] = __builtin_amdgcn_mfma_f32_16x16x32_bf16(pf[qs][1], mf1, accL[qs], 0, 0, 0);
        }
#pragma unroll
        for (int j = 0; j < 4; ++j) {
            const int vrow = (j * 16 + lrow) * 64;
            bf16x8 vf0 = *(const bf16x8*)&Vs[cur][vrow + ((g ^ (lrow & 7)) * 8)];
            bf16x8 vf1 = *(const bf16x8*)&Vs[cur][vrow + (((4 + g) ^ (lrow & 7)) * 8)];
#pragma unroll
            for (int qs = 0; qs < 2; ++qs) {
                accO[qs][j] = __builtin_amdgcn_mfma_f32_16x16x32_bf16(pf[qs][0], vf0, accO[qs][j], 0, 0, 0);
                accO[qs][j] = __builtin_amdgcn_mfma_f32_16x16x32_bf16(pf[qs][1], vf1, accO[qs][j], 0, 0, 0);
            }
        }
        __builtin_amdgcn_s_setprio(0);
    }

    // out[b][q][h*64 + d]
#pragma unroll
    for (int qs = 0; qs < 2; ++qs)
#pragma unroll
        for (int j = 0; j < 4; ++j)
#pragma unroll
            for (int r = 0; r < 4; ++r) {
                int qq = q0 + wid * 32 + qs * 16 + g * 4 + r;
                out[((size_t)(b * 2048 + qq)) * 1024 + h * 64 + j * 16 + lrow] =
                    accO[qs][j][r] / accL[qs][r];
            }
}

// ---------------------------------------------------------------------------
extern "C" void kernel_launch(void* const* d_in, const int* in_sizes, int n_in,
                              void* d_out, int out_size, void* d_ws, size_t ws_size,
                              hipStream_t stream) {
    const float* query    = (const float*)d_in[0];
    const float* key      = (const float*)d_in[1];
    const float* value    = (const float*)d_in[2];
    const int*   key_mask = (const int*)d_in[3];
    const float* Wq = (const float*)d_in[4];
    const float* bq = (const float*)d_in[5];
    const float* Wk = (const float*)d_in[6];
    const float* bk = (const float*)d_in[7];
    const float* Wv = (const float*)d_in[8];
    const float* bv = (const float*)d_in[9];
    float* out = (float*)d_out;

    char* ws = (char*)d_ws;
    unsigned short* Wt = (unsigned short*)ws;                      //  6 MB
    unsigned short* Pk = (unsigned short*)(ws + 6291456);          // 24 MB
    unsigned short* Xb = (unsigned short*)(ws + 31457280);         // 24 MB (54 MB total)

    if (ws_size >= 56623104ull) {
        prep<<<dim3(3072, 3), 256, 0, stream>>>(Wq, Wk, Wv, query, key, value, Wt, Xb);
        proj_g<<<dim3(32, 8, 3), 256, 0, stream>>>(Xb, Wt, bq, bk, bv, key_mask, Pk);
    } else {
        transpose_w3<<<dim3(32, 32, 3), 256, 0, stream>>>(Wq, Wk, Wv, Wt);
        proj_fb<<<dim3(32, 8, 3), 256, 0, stream>>>(query, key, value, Wt, bq, bk, bv, key_mask, Pk);
    }
    attn<<<dim3(32, 32), 128, 0, stream>>>(Pk, Pk + 4194304, Pk + 8388608, key_mask, out);
}